// Round 6
// baseline (331.697 us; speedup 1.0000x reference)
//
#include <hip/hip_runtime.h>
#include <hip/hip_bf16.h>

// DirectionalPropagation1D fused v6: B=16, C=64, H=256, W=256, N=4096 seqs.
// v6 = v5 with HALF the sequence tile: 8 seqs/block, 512 blocks, 64 KB LDS
// -> 2 blocks/CU (8 waves/CU) to test/fix the latency-parallelism wall that
// kept R2-R5 pinned at ~2.5 TB/s aggregate.
// Wave 0: full 64-channel recurrence, state in registers via permuted-Ws
//   K(h,g4,j) = 16*(2h + (j>>2)) + 4*g4 + (j&3)  (D-frag == next B-frag).
//   MFMA cols 8..15 duplicate cols 0..7 (lanes l15>=8 read same addresses).
// Waves 1-2: feat f32->bf16 double-buffered LDS stagers. Wave 3: out drain.
// One lgkm-only barrier per 16-step chunk.

typedef __attribute__((ext_vector_type(8))) short short8;
typedef __attribute__((ext_vector_type(4))) short short4v;
typedef __attribute__((ext_vector_type(2))) short short2v;
typedef __attribute__((ext_vector_type(4))) float f32x4;

union FragU { unsigned int u[4]; short8 v; };
union PkU { unsigned int u; short2v s2; };

__device__ __forceinline__ unsigned int pk2(float a, float b) {
    unsigned short lo = __bfloat16_as_ushort(__float2bfloat16(a));
    unsigned short hi = __bfloat16_as_ushort(__float2bfloat16(b));
    return (unsigned int)lo | ((unsigned int)hi << 16);
}
__device__ __forceinline__ float b2f(short x) {
    return __uint_as_float(((unsigned int)(unsigned short)x) << 16);
}

// feat staging [w16][n8][c64] bf16, XOR-swizzled (same function both sides).
__device__ __forceinline__ int fsi(int w, int n, int c) {
    return (w * 512 + n * 64 + c) ^ ((n & 7) << 3);
}
// out staging [o64][n8][w16] bf16, XOR-swizzled (same function both sides).
__device__ __forceinline__ int ogi(int o, int n, int w) {
    return (o * 128 + n * 16 + w) ^ ((((o >> 2) ^ (n >> 2)) & 3) << 2);
}

// LDS-only barrier: global traffic stays in flight across it.
#define BAR() asm volatile("s_waitcnt lgkmcnt(0)\n\ts_barrier" ::: "memory")

template<int V> struct Ic { static constexpr int value = V; };

__global__ __launch_bounds__(256, 2) void dp_v6_kernel(
    const float* __restrict__ feat, const float* __restrict__ conf,
    const float* __restrict__ Wi, const float* __restrict__ bi,
    const float* __restrict__ Ws, const float* __restrict__ bs,
    const float* __restrict__ bias, float* __restrict__ outp)
{
    __shared__ unsigned short fs[2][8192];   // 32 KB feat bf16, ping-pong
    __shared__ unsigned short og[2][8192];   // 32 KB out bf16, ping-pong

    const int tid = threadIdx.x;
    const int lane = tid & 63;
    const int wid = tid >> 6;
    const int l15 = lane & 15, g4 = lane >> 4;
    const int nb = blockIdx.x;
    const int b = nb >> 5, h0 = (nb & 31) * 8;   // 8 seqs per block

    const float* fb = feat + (size_t)b * 64 * 65536 + (size_t)h0 * 256;

    if (wid == 0) {
        // ================= recurrence wave =================
        const int nn = l15 & 7;                  // cols 8..15 duplicate 0..7
        const float* gb = conf + ((size_t)(b * 256) + h0 + nn) * 256;

        // Ai: natural k-order. As: permuted columns K(h,g4,j).
        FragU Ai[4][2], As[4][2];
        #pragma unroll
        for (int t = 0; t < 4; ++t)
            #pragma unroll
            for (int h = 0; h < 2; ++h) {
                const float* si = Wi + (16 * t + l15) * 64 + 32 * h + g4 * 8;
                const float* ss = Ws + (16 * t + l15) * 64;
                #pragma unroll
                for (int d = 0; d < 4; ++d) {
                    Ai[t][h].u[d] = pk2(si[2 * d], si[2 * d + 1]);
                    const int c0 = 16 * (2 * h + (d >> 1)) + 4 * g4 + 2 * (d & 1);
                    As[t][h].u[d] = pk2(ss[c0], ss[c0 + 1]);
                }
            }
        f32x4 binit[4];
        #pragma unroll
        for (int t = 0; t < 4; ++t)
            #pragma unroll
            for (int r = 0; r < 4; ++r) {
                int o = 16 * t + 4 * g4 + r;
                binit[t][r] = bi[o] + bs[o] + bias[o];
            }

        f32x4 gqA[4], gqB[4];
        #pragma unroll
        for (int q = 0; q < 4; ++q) gqA[q] = *(const f32x4*)(gb + 4 * q);

        FragU S0, S1;
        #pragma unroll
        for (int d = 0; d < 4; ++d) { S0.u[d] = 0u; S1.u[d] = 0u; }

        float curE[4][4];

        BAR();  // matches producers' post-prologue barrier

        auto run_chunk = [&](auto pc, int cc) {
            constexpr int P = decltype(pc)::value;
            f32x4 (&gqc)[4] = P ? gqB : gqA;
            f32x4 (&gqn)[4] = P ? gqA : gqB;
            const int w0 = cc * 16;
            #pragma unroll
            for (int u = 0; u < 16; ++u) {
                short8 F0 = *(const short8*)&fs[P][fsi(u, nn, 8 * g4)];
                short8 F1 = *(const short8*)&fs[P][fsi(u, nn, 32 + 8 * g4)];

                if (u == 2 && cc < 15) {
                    #pragma unroll
                    for (int q = 0; q < 4; ++q)
                        gqn[q] = *(const f32x4*)(gb + w0 + 16 + 4 * q);
                }

                f32x4 a0 = binit[0], a1 = binit[1], a2 = binit[2], a3 = binit[3];
                a0 = __builtin_amdgcn_mfma_f32_16x16x32_bf16(Ai[0][0].v, F0, a0, 0, 0, 0);
                a1 = __builtin_amdgcn_mfma_f32_16x16x32_bf16(Ai[1][0].v, F0, a1, 0, 0, 0);
                a2 = __builtin_amdgcn_mfma_f32_16x16x32_bf16(Ai[2][0].v, F0, a2, 0, 0, 0);
                a3 = __builtin_amdgcn_mfma_f32_16x16x32_bf16(Ai[3][0].v, F0, a3, 0, 0, 0);
                a0 = __builtin_amdgcn_mfma_f32_16x16x32_bf16(Ai[0][1].v, F1, a0, 0, 0, 0);
                a1 = __builtin_amdgcn_mfma_f32_16x16x32_bf16(Ai[1][1].v, F1, a1, 0, 0, 0);
                a2 = __builtin_amdgcn_mfma_f32_16x16x32_bf16(Ai[2][1].v, F1, a2, 0, 0, 0);
                a3 = __builtin_amdgcn_mfma_f32_16x16x32_bf16(Ai[3][1].v, F1, a3, 0, 0, 0);
                a0 = __builtin_amdgcn_mfma_f32_16x16x32_bf16(As[0][0].v, S0.v, a0, 0, 0, 0);
                a1 = __builtin_amdgcn_mfma_f32_16x16x32_bf16(As[1][0].v, S0.v, a1, 0, 0, 0);
                a2 = __builtin_amdgcn_mfma_f32_16x16x32_bf16(As[2][0].v, S0.v, a2, 0, 0, 0);
                a3 = __builtin_amdgcn_mfma_f32_16x16x32_bf16(As[3][0].v, S0.v, a3, 0, 0, 0);
                a0 = __builtin_amdgcn_mfma_f32_16x16x32_bf16(As[0][1].v, S1.v, a0, 0, 0, 0);
                a1 = __builtin_amdgcn_mfma_f32_16x16x32_bf16(As[1][1].v, S1.v, a1, 0, 0, 0);
                a2 = __builtin_amdgcn_mfma_f32_16x16x32_bf16(As[2][1].v, S1.v, a2, 0, 0, 0);
                a3 = __builtin_amdgcn_mfma_f32_16x16x32_bf16(As[3][1].v, S1.v, a3, 0, 0, 0);

                float cur[4][4];
                #pragma unroll
                for (int r = 0; r < 4; ++r) {
                    cur[0][r] = fmaxf(a0[r], 0.f);
                    cur[1][r] = fmaxf(a1[r], 0.f);
                    cur[2][r] = fmaxf(a2[r], 0.f);
                    cur[3][r] = fmaxf(a3[r], 0.f);
                }

                // out staging: pack w-pairs, b32 DS writes on odd steps.
                // Only the 8 real columns write (lanes l15>=8 are duplicates).
                if ((u & 1) == 0) {
                    #pragma unroll
                    for (int t = 0; t < 4; ++t)
                        #pragma unroll
                        for (int r = 0; r < 4; ++r) curE[t][r] = cur[t][r];
                } else if (l15 < 8) {
                    #pragma unroll
                    for (int t = 0; t < 4; ++t)
                        #pragma unroll
                        for (int r = 0; r < 4; ++r) {
                            PkU pk; pk.u = pk2(curE[t][r], cur[t][r]);
                            *(short2v*)&og[P][ogi(16 * t + 4 * g4 + r, l15, u - 1)] = pk.s2;
                        }
                }

                // rebuild state fragments for step w+1 (lane-local!)
                if (!(cc == 15 && u == 15)) {
                    float gv = (u < 15) ? gqc[(u + 1) >> 2][(u + 1) & 3] : gqn[0][0];
                    float g0[4], g1[4], g2[4], g3[4];
                    #pragma unroll
                    for (int r = 0; r < 4; ++r) {
                        g0[r] = cur[0][r] * gv; g1[r] = cur[1][r] * gv;
                        g2[r] = cur[2][r] * gv; g3[r] = cur[3][r] * gv;
                    }
                    S0.u[0] = pk2(g0[0], g0[1]); S0.u[1] = pk2(g0[2], g0[3]);
                    S0.u[2] = pk2(g1[0], g1[1]); S0.u[3] = pk2(g1[2], g1[3]);
                    S1.u[0] = pk2(g2[0], g2[1]); S1.u[1] = pk2(g2[2], g2[3]);
                    S1.u[2] = pk2(g3[0], g3[1]); S1.u[3] = pk2(g3[2], g3[3]);
                }
            }
            BAR();  // end of chunk
        };

        #pragma unroll 1
        for (int c2 = 0; c2 < 8; ++c2) {
            run_chunk(Ic<0>{}, 2 * c2);
            run_chunk(Ic<1>{}, 2 * c2 + 1);
        }
    } else if (wid <= 2) {
        // ================= feat stagers (waves 1,2) =================
        // wave handles 16 c-pairs (32 c): cp = base + 8*pi + (lane>>3), n = lane&7.
        const int cpb = (wid - 1) * 16 + (lane >> 3);
        const int n = lane & 7;

        auto stage = [&](int buf, int w0) {
            f32x4 ra[2][2][4];  // [pi][row][w-quad], statically indexed
            #pragma unroll
            for (int pi = 0; pi < 2; ++pi) {
                const int cp = cpb + 8 * pi;
                const float* p0 = fb + (size_t)(2 * cp) * 65536 + n * 256 + w0;
                #pragma unroll
                for (int row = 0; row < 2; ++row)
                    #pragma unroll
                    for (int q = 0; q < 4; ++q)
                        ra[pi][row][q] = *(const f32x4*)(p0 + row * 65536 + 4 * q);
            }
            #pragma unroll
            for (int pi = 0; pi < 2; ++pi) {
                const int cp = cpb + 8 * pi;
                #pragma unroll
                for (int q = 0; q < 4; ++q)
                    #pragma unroll
                    for (int e = 0; e < 4; ++e) {
                        PkU pk; pk.u = pk2(ra[pi][0][q][e], ra[pi][1][q][e]);
                        *(short2v*)&fs[buf][fsi(4 * q + e, n, 2 * cp)] = pk.s2;
                    }
            }
        };

        stage(0, 0);
        BAR();
        #pragma unroll 1
        for (int cc = 0; cc < 16; ++cc) {
            if (cc < 15) stage((cc + 1) & 1, (cc + 1) * 16);
            BAR();
        }
    } else {
        // ================= out drainer (wave 3) =================
        const int n = (lane >> 2) & 7, wq = lane & 3, olo = lane >> 5;

        auto drain = [&](int buf, int wpr) {
            #pragma unroll 8
            for (int k = 0; k < 32; ++k) {
                const int o = 2 * k + olo;
                short4v d = *(const short4v*)&og[buf][ogi(o, n, 4 * wq)];
                f32x4 o4 = { b2f(d.x), b2f(d.y), b2f(d.z), b2f(d.w) };
                *(f32x4*)(outp + ((size_t)(b * 64 + o) * 256 + h0 + n) * 256 + wpr + 4 * wq) = o4;
            }
        };

        BAR();
        #pragma unroll 1
        for (int cc = 0; cc < 16; ++cc) {
            if (cc > 0) drain((cc - 1) & 1, (cc - 1) * 16);
            BAR();
        }
        drain(1, 240);  // chunk 15
    }
}

extern "C" void kernel_launch(void* const* d_in, const int* in_sizes, int n_in,
                              void* d_out, int out_size, void* d_ws, size_t ws_size,
                              hipStream_t stream) {
    const float* feat = (const float*)d_in[0];
    const float* conf = (const float*)d_in[1];
    const float* Wi   = (const float*)d_in[2];
    const float* bi   = (const float*)d_in[3];
    const float* Ws   = (const float*)d_in[4];
    const float* bs   = (const float*)d_in[5];
    const float* bias = (const float*)d_in[6];
    float* out = (float*)d_out;
    (void)d_ws; (void)ws_size; (void)in_sizes; (void)n_in; (void)out_size;

    dp_v6_kernel<<<512, 256, 0, stream>>>(feat, conf, Wi, bi, Ws, bs, bias, out);
}